// Round 1
// baseline (410.073 us; speedup 1.0000x reference)
//
#include <hip/hip_runtime.h>
#include <math.h>

typedef __attribute__((ext_vector_type(8))) short short8;
typedef __attribute__((ext_vector_type(4))) float floatx4;

#define EPS 1e-12f

// ws layout (u16 element offsets unless noted)
#define WS_AMAIN 0        // [400][128] rows: 0-127 W1se3, 128-255 W2se3, 256-383 vsdir,
                          //            384 colmean(W1se3), 385 colmean(W2se3), 386 ones/128, 387-399 zero
#define WS_ASCAL 51200    // [256][128] rows: 0-127 sv_W, 128-255 ss_W
#define WS_AFC   83968    // [128][256] crossfc_se3 (k: 0-127 pairs with cr, 128-255 with v2)
#define WS_AVS   116736   // [128][128] vs_W
#define WS_VDR_B 266240   // byte offset: fp32[128] rowsum(vsdir)

__device__ __forceinline__ unsigned short f2bf(float f) {
  union { float f; unsigned u; } v; v.f = f;
  unsigned r = v.u + 0x7FFFu + ((v.u >> 16) & 1u);
  return (unsigned short)(r >> 16);
}
__device__ __forceinline__ float bf2f(unsigned u16) {
  union { unsigned u; float f; } v; v.u = u16 << 16;
  return v.f;
}

__device__ __forceinline__ float block_sum_256(float v, float* red) {
  const int t = threadIdx.x;
  red[t] = v;
  __syncthreads();
  for (int s = 128; s > 0; s >>= 1) {
    if (t < s) red[t] += red[t + s];
    __syncthreads();
  }
  float r = red[0];
  __syncthreads();
  return r;
}

__global__ __launch_bounds__(256) void k_pre(
    const float* __restrict__ weight, const float* __restrict__ sv_W,
    const float* __restrict__ cross_w, const float* __restrict__ crossfc_w,
    const float* __restrict__ vsdir_w, const float* __restrict__ vs_W,
    const float* __restrict__ ss_W, unsigned short* __restrict__ wsu,
    float* __restrict__ vdr) {
  __shared__ float red[256];
  const int o = blockIdx.x;   // 128 blocks, one per output row
  const int t = threadIdx.x;  // 256

  float s1 = block_sum_256((t < 127) ? weight[o * 127 + t] : 0.f, red);
  if (t < 128)
    wsu[WS_AMAIN + o * 128 + t] = f2bf((t < 127) ? weight[o * 127 + t] : 1.f - s1);

  float s2 = block_sum_256((t < 127) ? cross_w[o * 127 + t] : 0.f, red);
  if (t < 128)
    wsu[WS_AMAIN + (128 + o) * 128 + t] = f2bf((t < 127) ? cross_w[o * 127 + t] : 1.f - s2);

  float s4 = block_sum_256((t < 128) ? vsdir_w[o * 128 + t] : 0.f, red);
  if (t < 128)
    wsu[WS_AMAIN + (256 + o) * 128 + t] = f2bf(vsdir_w[o * 128 + t]);
  if (t == 0) vdr[o] = s4;

  float s3 = block_sum_256((t < 255) ? crossfc_w[o * 255 + t] : 0.f, red);
  wsu[WS_AFC + o * 256 + t] = f2bf((t < 255) ? crossfc_w[o * 255 + t] : 1.f - s3);

  if (t < 128) {
    wsu[WS_ASCAL + o * 128 + t]         = f2bf(sv_W[o * 128 + t]);
    wsu[WS_ASCAL + (128 + o) * 128 + t] = f2bf(ss_W[o * 128 + t]);
    wsu[WS_AVS + o * 128 + t]           = f2bf(vs_W[o * 128 + t]);
  }
  if (o == 0) {
    if (t < 128) wsu[WS_AMAIN + 386 * 128 + t] = f2bf(1.f / 128.f);
    for (int l = t; l < 13 * 128; l += 256) wsu[WS_AMAIN + 387 * 128 + l] = 0;
  }
}

// colmean rows (384: W1se3, 385: W2se3) from already-written bf16 rows
__global__ void k_mean(unsigned short* __restrict__ wsu) {
  const int g = blockIdx.x, c = threadIdx.x;  // 2 blocks x 128 threads
  float s = 0.f;
  for (int o = 0; o < 128; ++o) s += bf2f(wsu[WS_AMAIN + (g * 128 + o) * 128 + c]);
  wsu[WS_AMAIN + (384 + g) * 128 + c] = f2bf(s * (1.f / 128.f));
}

// Fused MFMA kernel, 512 threads = 8 waves = 2 waves/SIMD (was 4 waves = 1/SIMD).
// Wave = (rg, cg): cg = col-group (16 cols), rg = row-group (64 of 128 output rows).
// Channel-wise reductions (s2v norm, sfv norm, v2 mean, cross norm) combine the
// two row-group partners through xred[] scratch; those barriers also order all
// LDS overwrite hazards (sB s->sfn, xB x->cr, v2B) across partner waves.
__global__ __launch_bounds__(512, 2) void k_main(
    const float* __restrict__ v_in, const float* __restrict__ s_in,
    const unsigned short* __restrict__ wsu, const float* __restrict__ vdr,
    const float* __restrict__ sv_b, const float* __restrict__ vs_b,
    const float* __restrict__ ss_b,
    float* __restrict__ v_out, float* __restrict__ s_out) {
  const int t = threadIdx.x;
  const int wave = t >> 6, lane = t & 63;
  const int q = lane >> 4, ln = lane & 15;
  const int cg = wave & 3;        // column group: cols cg*16..cg*16+15
  const int rg = wave >> 2;       // row group: output rows rg*64..rg*64+63
  const int b = blockIdx.x >> 6;
  const int n0 = (blockIdx.x & 63) * 64;
  const int mycol = cg * 16 + ln;
  const int rb = rg * 64;
  const int rc = cg * 16 + ln;    // scratch column index

  __shared__ __align__(16) unsigned short xB[192 * 136];   // x; later cr
  __shared__ __align__(16) unsigned short v2B[192 * 136];  // v2
  __shared__ __align__(16) unsigned short sB[64 * 136];    // s; later sfn
  __shared__ float xred[6][2][64];  // cross-rowgroup reduction scratch

  // ---- staging: global fp32 -> bf16 LDS in B layout ----
  {
    const float* vb = v_in + (size_t)b * (128 * 3 * 4096) + n0;
    for (int l = t; l < 6144; l += 512) {
      const int c = l / 48, r = l % 48;
      const int v = r >> 4, j4 = (r & 15) * 4;
      const float4 f = *(const float4*)(vb + (size_t)(c * 3 + v) * 4096 + j4);
      const int base = (v * 64 + j4) * 136 + c;
      xB[base]       = f2bf(f.x);
      xB[base + 136] = f2bf(f.y);
      xB[base + 272] = f2bf(f.z);
      xB[base + 408] = f2bf(f.w);
    }
    const float* sb = s_in + (size_t)b * (128 * 4096) + n0;
    for (int l = t; l < 2048; l += 512) {
      const int c = l >> 4, j4 = (l & 15) * 4;
      const float4 f = *(const float4*)(sb + (size_t)c * 4096 + j4);
      const int base = j4 * 136 + c;
      sB[base]       = f2bf(f.x);
      sB[base + 136] = f2bf(f.y);
      sB[base + 272] = f2bf(f.z);
      sB[base + 408] = f2bf(f.w);
    }
  }
  __syncthreads();  // B1

  // ---- g0: sv/ss GEMM (A_scal rows rb..rb+63 and 128+rb..128+rb+63) ----
  floatx4 accS[8];
#pragma unroll
  for (int i = 0; i < 8; ++i) accS[i] = (floatx4){0.f, 0.f, 0.f, 0.f};
#pragma unroll
  for (int k = 0; k < 4; ++k) {
    const short8 bf = *(const short8*)(sB + mycol * 136 + k * 32 + q * 8);
    const unsigned short* ap = wsu + WS_ASCAL + (rb + ln) * 128 + k * 32 + q * 8;
#pragma unroll
    for (int mt = 0; mt < 4; ++mt)
      accS[mt] = __builtin_amdgcn_mfma_f32_16x16x32_bf16(
          *(const short8*)(ap + mt * 2048), bf, accS[mt], 0, 0, 0);
    const unsigned short* ap2 = ap + 128 * 128;
#pragma unroll
    for (int mt = 0; mt < 4; ++mt)
      accS[4 + mt] = __builtin_amdgcn_mfma_f32_16x16x32_bf16(
          *(const short8*)(ap2 + mt * 2048), bf, accS[4 + mt], 0, 0, 0);
  }
  float s2v[4][4], tssb[4][4];
  {
    float nrm = 0.f;
#pragma unroll
    for (int mt = 0; mt < 4; ++mt) {
      const float4 bb = *(const float4*)(sv_b + rb + mt * 16 + q * 4);
      const float* bp = (const float*)&bb;
#pragma unroll
      for (int r = 0; r < 4; ++r) {
        const float tv = accS[mt][r] + bp[r];
        s2v[mt][r] = tv;
        nrm += tv * tv;
      }
    }
    nrm += __shfl_xor(nrm, 16);
    nrm += __shfl_xor(nrm, 32);
    if (lane < 16) xred[0][rg][rc] = nrm;
    __syncthreads();  // B2
    const float ntot = xred[0][0][rc] + xred[0][1][rc];
    const float inv = 1.f / fmaxf(sqrtf(ntot), EPS);
#pragma unroll
    for (int mt = 0; mt < 4; ++mt)
#pragma unroll
      for (int r = 0; r < 4; ++r) s2v[mt][r] *= inv;
#pragma unroll
    for (int mt = 0; mt < 4; ++mt) {
      const float4 b1 = *(const float4*)(ss_b + rb + mt * 16 + q * 4);
      const float4 b2 = *(const float4*)(vs_b + rb + mt * 16 + q * 4);
      const float* p1 = (const float*)&b1;
      const float* p2 = (const float*)&b2;
#pragma unroll
      for (int r = 0; r < 4; ++r) tssb[mt][r] = accS[4 + mt][r] + p1[r] + p2[r];
    }
  }

  // ---- g1: dd (vsdir rows rb..rb+63) + means-row tile ----
  floatx4 accD[5][3];
#pragma unroll
  for (int i = 0; i < 5; ++i)
#pragma unroll
    for (int v = 0; v < 3; ++v) accD[i][v] = (floatx4){0.f, 0.f, 0.f, 0.f};
#pragma unroll
  for (int k = 0; k < 4; ++k) {
    short8 bfv[3];
#pragma unroll
    for (int v = 0; v < 3; ++v)
      bfv[v] = *(const short8*)(xB + (v * 64 + mycol) * 136 + k * 32 + q * 8);
    const unsigned short* ap = wsu + WS_AMAIN + (256 + rb + ln) * 128 + k * 32 + q * 8;
#pragma unroll
    for (int i = 0; i < 4; ++i) {
      const short8 a = *(const short8*)(ap + i * 2048);
#pragma unroll
      for (int v = 0; v < 3; ++v)
        accD[i][v] = __builtin_amdgcn_mfma_f32_16x16x32_bf16(a, bfv[v], accD[i][v], 0, 0, 0);
    }
    const unsigned short* am = wsu + WS_AMAIN + (384 + ln) * 128 + k * 32 + q * 8;
    const short8 a4 = *(const short8*)am;
#pragma unroll
    for (int v = 0; v < 3; ++v)
      accD[4][v] = __builtin_amdgcn_mfma_f32_16x16x32_bf16(a4, bfv[v], accD[4][v], 0, 0, 0);
  }
  float xm[3], vmn[3], dmn[3];
#pragma unroll
  for (int v = 0; v < 3; ++v) {
    vmn[v] = __shfl(accD[4][v][0], ln);   // row 384
    dmn[v] = __shfl(accD[4][v][1], ln);   // row 385
    xm[v]  = __shfl(accD[4][v][2], ln);   // row 386
  }

  // ---- scalar path: sfv -> sfn -> LDS (over sB, own k-half) ----
  {
    float sfv[4][4];
    float ssum = 0.f;
#pragma unroll
    for (int mt = 0; mt < 4; ++mt) {
      const float4 rs4 = *(const float4*)(vdr + rb + mt * 16 + q * 4);
      const float* rp = (const float*)&rs4;
      uint2 pk[3];
#pragma unroll
      for (int v = 0; v < 3; ++v)
        pk[v] = *(const uint2*)(xB + (v * 64 + mycol) * 136 + rb + mt * 16 + q * 4);
#pragma unroll
      for (int r = 0; r < 4; ++r) {
        float d[3], xr[3];
#pragma unroll
        for (int v = 0; v < 3; ++v) {
          d[v] = accD[mt][v][r] - rp[r] * xm[v];
          const unsigned w = (r < 2) ? pk[v].x : pk[v].y;
          xr[v] = bf2f((w >> ((r & 1) * 16)) & 0xffffu) - xm[v];
        }
        const float n2 = d[0] * d[0] + d[1] * d[1] + d[2] * d[2];
        const float dinv = 1.f / fmaxf(sqrtf(n2), EPS);
        const float sv_ = (xr[0] * d[0] + xr[1] * d[1] + xr[2] * d[2]) * dinv;
        sfv[mt][r] = sv_;
        ssum += sv_ * sv_;
      }
    }
    ssum += __shfl_xor(ssum, 16);
    ssum += __shfl_xor(ssum, 32);
    if (lane < 16) xred[1][rg][rc] = ssum;
    __syncthreads();  // B3
    const float stot = xred[1][0][rc] + xred[1][1][rc];
    const float sinv = 1.f / fmaxf(sqrtf(stot), EPS);
#pragma unroll
    for (int mt = 0; mt < 4; ++mt) {
      const unsigned lo = (unsigned)f2bf(sfv[mt][0] * sinv) |
                          ((unsigned)f2bf(sfv[mt][1] * sinv) << 16);
      const unsigned hi = (unsigned)f2bf(sfv[mt][2] * sinv) |
                          ((unsigned)f2bf(sfv[mt][3] * sinv) << 16);
      *(uint2*)(sB + mycol * 136 + rb + mt * 16 + q * 4) = make_uint2(lo, hi);
    }
  }

  // ---- g2a: v1 = W1se3@x (rows rb..rb+63), then v2 in-place; write v2B ----
  floatx4 accV[4][3];
#pragma unroll
  for (int i = 0; i < 4; ++i)
#pragma unroll
    for (int v = 0; v < 3; ++v) accV[i][v] = (floatx4){0.f, 0.f, 0.f, 0.f};
#pragma unroll
  for (int k = 0; k < 4; ++k) {
    short8 bfv[3];
#pragma unroll
    for (int v = 0; v < 3; ++v)
      bfv[v] = *(const short8*)(xB + (v * 64 + mycol) * 136 + k * 32 + q * 8);
    const unsigned short* ap = wsu + WS_AMAIN + (rb + ln) * 128 + k * 32 + q * 8;
#pragma unroll
    for (int mt = 0; mt < 4; ++mt) {
      const short8 a = *(const short8*)(ap + mt * 2048);
#pragma unroll
      for (int v = 0; v < 3; ++v)
        accV[mt][v] = __builtin_amdgcn_mfma_f32_16x16x32_bf16(a, bfv[v], accV[mt][v], 0, 0, 0);
    }
  }
  float v2m[3];
#pragma unroll
  for (int v = 0; v < 3; ++v) {
    float s = 0.f;
#pragma unroll
    for (int mt = 0; mt < 4; ++mt)
#pragma unroll
      for (int r = 0; r < 4; ++r) {
        const float val = (accV[mt][v][r] - vmn[v]) * s2v[mt][r] + vmn[v];
        accV[mt][v][r] = val;
        s += val;
      }
    s += __shfl_xor(s, 16);
    s += __shfl_xor(s, 32);
    if (lane < 16) xred[2 + v][rg][rc] = s;
  }
  __syncthreads();  // B4
#pragma unroll
  for (int v = 0; v < 3; ++v)
    v2m[v] = (xred[2 + v][0][rc] + xred[2 + v][1][rc]) * (1.f / 128.f);
#pragma unroll
  for (int mt = 0; mt < 4; ++mt)
#pragma unroll
    for (int v = 0; v < 3; ++v) {
      const unsigned lo = (unsigned)f2bf(accV[mt][v][0]) |
                          ((unsigned)f2bf(accV[mt][v][1]) << 16);
      const unsigned hi = (unsigned)f2bf(accV[mt][v][2]) |
                          ((unsigned)f2bf(accV[mt][v][3]) << 16);
      *(uint2*)(v2B + (v * 64 + mycol) * 136 + rb + mt * 16 + q * 4) = make_uint2(lo, hi);
    }

  // ---- g2b: vd = W2se3@x (rows rb..rb+63), cross branch; write cr over xB ----
  floatx4 accW[4][3];
#pragma unroll
  for (int i = 0; i < 4; ++i)
#pragma unroll
    for (int v = 0; v < 3; ++v) accW[i][v] = (floatx4){0.f, 0.f, 0.f, 0.f};
#pragma unroll
  for (int k = 0; k < 4; ++k) {
    short8 bfv[3];
#pragma unroll
    for (int v = 0; v < 3; ++v)
      bfv[v] = *(const short8*)(xB + (v * 64 + mycol) * 136 + k * 32 + q * 8);
    const unsigned short* ap = wsu + WS_AMAIN + (128 + rb + ln) * 128 + k * 32 + q * 8;
#pragma unroll
    for (int mt = 0; mt < 4; ++mt) {
      const short8 a = *(const short8*)(ap + mt * 2048);
#pragma unroll
      for (int v = 0; v < 3; ++v)
        accW[mt][v] = __builtin_amdgcn_mfma_f32_16x16x32_bf16(a, bfv[v], accW[mt][v], 0, 0, 0);
    }
  }
  float an[4][4];
  float csum = 0.f;
#pragma unroll
  for (int mt = 0; mt < 4; ++mt)
#pragma unroll
    for (int r = 0; r < 4; ++r) {
      const float a0 = accW[mt][0][r] - dmn[0];
      const float a1 = accW[mt][1][r] - dmn[1];
      const float a2 = accW[mt][2][r] - dmn[2];
      accW[mt][0][r] = a0; accW[mt][1][r] = a1; accW[mt][2][r] = a2;
      const float n2 = a0 * a0 + a1 * a1 + a2 * a2;
      an[mt][r] = sqrtf(n2);
      csum += n2;
    }
  csum += __shfl_xor(csum, 16);
  csum += __shfl_xor(csum, 32);
  if (lane < 16) xred[5][rg][rc] = csum;
  __syncthreads();  // B5 (also: all waves' x-reads of xB are complete)
  const float ctot = xred[5][0][rc] + xred[5][1][rc];
  const float cninv = 1.f / fmaxf(sqrtf(ctot), EPS);
#pragma unroll
  for (int mt = 0; mt < 4; ++mt) {
    float crv[3][4];
#pragma unroll
    for (int r = 0; r < 4; ++r) {
      const float sc = an[mt][r] / fmaxf(an[mt][r], EPS) * cninv;
      const float h0 = accW[mt][0][r] * sc;
      const float h1 = accW[mt][1][r] * sc;
      const float h2 = accW[mt][2][r] * sc;
      const float w0 = accV[mt][0][r], w1 = accV[mt][1][r], w2 = accV[mt][2][r];
      const float g0 = w0 - v2m[0], g1 = w1 - v2m[1], g2 = w2 - v2m[2];
      crv[0][r] = h1 * g2 - h2 * g1 + w0;
      crv[1][r] = h2 * g0 - h0 * g2 + w1;
      crv[2][r] = h0 * g1 - h1 * g0 + w2;
    }
#pragma unroll
    for (int v = 0; v < 3; ++v) {
      const unsigned lo = (unsigned)f2bf(crv[v][0]) | ((unsigned)f2bf(crv[v][1]) << 16);
      const unsigned hi = (unsigned)f2bf(crv[v][2]) | ((unsigned)f2bf(crv[v][3]) << 16);
      *(uint2*)(xB + (v * 64 + mycol) * 136 + rb + mt * 16 + q * 4) = make_uint2(lo, hi);
    }
  }
  __syncthreads();  // B6: cr/v2/sfn complete -> g3 may read full K

  // ---- g3: crossfc (K=256 over [cr;v2]) + vs (K=128 over sfn), rows rb..rb+63 ----
  floatx4 accO[4][3];
  floatx4 accP[4];
#pragma unroll
  for (int i = 0; i < 4; ++i) {
    accP[i] = (floatx4){0.f, 0.f, 0.f, 0.f};
#pragma unroll
    for (int v = 0; v < 3; ++v) accO[i][v] = (floatx4){0.f, 0.f, 0.f, 0.f};
  }
#pragma unroll
  for (int ks = 0; ks < 8; ++ks) {
    const unsigned short* src = (ks < 4) ? xB : v2B;
    const int kk = ks & 3;
    short8 bfv[3];
#pragma unroll
    for (int v = 0; v < 3; ++v)
      bfv[v] = *(const short8*)(src + (v * 64 + mycol) * 136 + kk * 32 + q * 8);
    const unsigned short* afc = wsu + WS_AFC + (rb + ln) * 256 + ks * 32 + q * 8;
#pragma unroll
    for (int mt = 0; mt < 4; ++mt) {
      const short8 a = *(const short8*)(afc + mt * 4096);
#pragma unroll
      for (int v = 0; v < 3; ++v)
        accO[mt][v] = __builtin_amdgcn_mfma_f32_16x16x32_bf16(a, bfv[v], accO[mt][v], 0, 0, 0);
    }
    if (ks < 4) {
      const short8 bfs = *(const short8*)(sB + mycol * 136 + kk * 32 + q * 8);
      const unsigned short* avs = wsu + WS_AVS + (rb + ln) * 128 + kk * 32 + q * 8;
#pragma unroll
      for (int mt = 0; mt < 4; ++mt)
        accP[mt] = __builtin_amdgcn_mfma_f32_16x16x32_bf16(
            *(const short8*)(avs + mt * 2048), bfs, accP[mt], 0, 0, 0);
    }
  }

  // ---- epilogue stores (rows rb..rb+63) ----
  const int gc = n0 + mycol;
  float* vob = v_out + (size_t)b * (128 * 3 * 4096) + gc;
  float* sob = s_out + (size_t)b * (128 * 4096) + gc;
#pragma unroll
  for (int mt = 0; mt < 4; ++mt)
#pragma unroll
    for (int r = 0; r < 4; ++r) {
      const int o = rb + mt * 16 + q * 4 + r;
#pragma unroll
      for (int v = 0; v < 3; ++v)
        vob[(size_t)(o * 3 + v) * 4096] = accO[mt][v][r];
      sob[(size_t)o * 4096] = accP[mt][r] + tssb[mt][r];
    }
}

extern "C" void kernel_launch(void* const* d_in, const int* in_sizes, int n_in,
                              void* d_out, int out_size, void* d_ws, size_t ws_size,
                              hipStream_t stream) {
  const float* v_in      = (const float*)d_in[0];
  const float* s_in      = (const float*)d_in[1];
  const float* weight    = (const float*)d_in[2];
  const float* sv_W      = (const float*)d_in[3];
  const float* sv_b      = (const float*)d_in[4];
  const float* cross_w   = (const float*)d_in[5];
  const float* crossfc_w = (const float*)d_in[6];
  const float* vsdir_w   = (const float*)d_in[7];
  const float* vs_W      = (const float*)d_in[8];
  const float* vs_b      = (const float*)d_in[9];
  const float* ss_W      = (const float*)d_in[10];
  const float* ss_b      = (const float*)d_in[11];

  float* out = (float*)d_out;
  float* v_out = out;                                  // [16][128][3][4096]
  float* s_out = out + (size_t)16 * 128 * 3 * 4096;    // [16][128][4096]
  unsigned short* wsu = (unsigned short*)d_ws;
  float* vdr = (float*)((char*)d_ws + WS_VDR_B);

  hipLaunchKernelGGL(k_pre, dim3(128), dim3(256), 0, stream,
                     weight, sv_W, cross_w, crossfc_w, vsdir_w, vs_W, ss_W, wsu, vdr);
  hipLaunchKernelGGL(k_mean, dim3(2), dim3(128), 0, stream, wsu);
  hipLaunchKernelGGL(k_main, dim3(1024), dim3(512), 0, stream,
                     v_in, s_in, wsu, vdr, sv_b, vs_b, ss_b, v_out, s_out);
}

// Round 2
// 393.619 us; speedup vs baseline: 1.0418x; 1.0418x over previous
//
#include <hip/hip_runtime.h>
#include <math.h>

typedef __attribute__((ext_vector_type(8))) short short8;
typedef __attribute__((ext_vector_type(4))) float floatx4;

#define EPS 1e-12f

// ws layout (u16 element offsets unless noted)
#define WS_AMAIN 0        // [400][128] rows: 0-127 W1se3, 128-255 W2se3, 256-383 vsdir,
                          //            384-399 zero except 386 = ones/128
#define WS_ASCAL 51200    // [256][128] rows: 0-127 sv_W, 128-255 ss_W
#define WS_AFC   83968    // [128][256] crossfc_se3 (k: 0-127 pairs with cr, 128-255 with v2)
#define WS_AVS   116736   // [128][128] vs_W
#define WS_VDR_B 266240   // byte offset: fp32[128] rowsum(vsdir)

__device__ __forceinline__ unsigned short f2bf(float f) {
  union { float f; unsigned u; } v; v.f = f;
  unsigned r = v.u + 0x7FFFu + ((v.u >> 16) & 1u);
  return (unsigned short)(r >> 16);
}
__device__ __forceinline__ float bf2f(unsigned u16) {
  union { unsigned u; float f; } v; v.u = u16 << 16;
  return v.f;
}

__device__ __forceinline__ float block_sum_256(float v, float* red) {
  const int t = threadIdx.x;
  red[t] = v;
  __syncthreads();
  for (int s = 128; s > 0; s >>= 1) {
    if (t < s) red[t] += red[t + s];
    __syncthreads();
  }
  float r = red[0];
  __syncthreads();
  return r;
}

__global__ __launch_bounds__(256) void k_pre(
    const float* __restrict__ weight, const float* __restrict__ sv_W,
    const float* __restrict__ cross_w, const float* __restrict__ crossfc_w,
    const float* __restrict__ vsdir_w, const float* __restrict__ vs_W,
    const float* __restrict__ ss_W, unsigned short* __restrict__ wsu,
    float* __restrict__ vdr) {
  __shared__ float red[256];
  const int o = blockIdx.x;   // 128 blocks, one per output row
  const int t = threadIdx.x;  // 256

  float s1 = block_sum_256((t < 127) ? weight[o * 127 + t] : 0.f, red);
  if (t < 128)
    wsu[WS_AMAIN + o * 128 + t] = f2bf((t < 127) ? weight[o * 127 + t] : 1.f - s1);

  float s2 = block_sum_256((t < 127) ? cross_w[o * 127 + t] : 0.f, red);
  if (t < 128)
    wsu[WS_AMAIN + (128 + o) * 128 + t] = f2bf((t < 127) ? cross_w[o * 127 + t] : 1.f - s2);

  float s4 = block_sum_256((t < 128) ? vsdir_w[o * 128 + t] : 0.f, red);
  if (t < 128)
    wsu[WS_AMAIN + (256 + o) * 128 + t] = f2bf(vsdir_w[o * 128 + t]);
  if (t == 0) vdr[o] = s4;

  float s3 = block_sum_256((t < 255) ? crossfc_w[o * 255 + t] : 0.f, red);
  wsu[WS_AFC + o * 256 + t] = f2bf((t < 255) ? crossfc_w[o * 255 + t] : 1.f - s3);

  if (t < 128) {
    wsu[WS_ASCAL + o * 128 + t]         = f2bf(sv_W[o * 128 + t]);
    wsu[WS_ASCAL + (128 + o) * 128 + t] = f2bf(ss_W[o * 128 + t]);
    wsu[WS_AVS + o * 128 + t]           = f2bf(vs_W[o * 128 + t]);
  }
  if (o == 0) {
    // rows 384-399: zero, then row 386 = ones/128 (per-thread order is safe:
    // offset 386*128+c is written in the zero loop by thread c, then by the
    // ones store from the same thread c).
    for (int l = t; l < 16 * 128; l += 256) wsu[WS_AMAIN + 384 * 128 + l] = 0;
    if (t < 128) wsu[WS_AMAIN + 386 * 128 + t] = f2bf(1.f / 128.f);
  }
}

// Fused MFMA kernel. 32-column N-tile, 512 threads = 8 waves (2 cg x 4 rg),
// LDS 65 KB -> 2 blocks/CU = 16 waves/CU. Wave owns cols [cg*16,cg*16+16) and
// output rows [rg*32, rg*32+32). Channel reductions (s2v/sfv norms, vmn, v2m,
// dmn, csum) go through xred[] with >=1 full barrier between any read of a
// slot and its reuse-write.
__global__ __launch_bounds__(512, 4) void k_main(
    const float* __restrict__ v_in, const float* __restrict__ s_in,
    const unsigned short* __restrict__ wsu, const float* __restrict__ vdr,
    const float* __restrict__ sv_b, const float* __restrict__ vs_b,
    const float* __restrict__ ss_b,
    float* __restrict__ v_out, float* __restrict__ s_out) {
  const int t = threadIdx.x;
  const int wave = t >> 6, lane = t & 63;
  const int q = lane >> 4, ln = lane & 15;
  const int cg = wave & 1;        // column group: cols cg*16..cg*16+15
  const int rg = wave >> 1;       // row group: output rows rg*32..rg*32+31
  const int b = blockIdx.x >> 7;
  const int n0 = (blockIdx.x & 127) * 32;
  const int mycol = cg * 16 + ln;
  const int rb = rg * 32;

  __shared__ __align__(16) unsigned short xB[96 * 136];   // x; later cr
  __shared__ __align__(16) unsigned short v2B[96 * 136];  // v2
  __shared__ __align__(16) unsigned short sB[32 * 136];   // s; later sfn
  __shared__ float xred[8][4][32];  // cross-rowgroup reduction scratch

  // ---- staging: global fp32 -> bf16 LDS in B layout ----
  {
    const float* vb = v_in + (size_t)b * (128 * 3 * 4096) + n0;
    for (int l = t; l < 3072; l += 512) {
      const int c = l / 24, r = l % 24;
      const int v = r >> 3, j4 = (r & 7) * 4;
      const float4 f = *(const float4*)(vb + (size_t)(c * 3 + v) * 4096 + j4);
      const int base = (v * 32 + j4) * 136 + c;
      xB[base]       = f2bf(f.x);
      xB[base + 136] = f2bf(f.y);
      xB[base + 272] = f2bf(f.z);
      xB[base + 408] = f2bf(f.w);
    }
    const float* sb = s_in + (size_t)b * (128 * 4096) + n0;
    for (int l = t; l < 1024; l += 512) {
      const int c = l >> 3, j4 = (l & 7) * 4;
      const float4 f = *(const float4*)(sb + (size_t)c * 4096 + j4);
      const int base = j4 * 136 + c;
      sB[base]       = f2bf(f.x);
      sB[base + 136] = f2bf(f.y);
      sB[base + 272] = f2bf(f.z);
      sB[base + 408] = f2bf(f.w);
    }
  }
  __syncthreads();  // B1

  // ---- g0: sv/ss GEMM (A_scal rows rb..rb+31 and 128+rb..128+rb+31) ----
  floatx4 accS[4];
#pragma unroll
  for (int i = 0; i < 4; ++i) accS[i] = (floatx4){0.f, 0.f, 0.f, 0.f};
#pragma unroll
  for (int k = 0; k < 4; ++k) {
    const short8 bf = *(const short8*)(sB + mycol * 136 + k * 32 + q * 8);
    const unsigned short* ap = wsu + WS_ASCAL + (rb + ln) * 128 + k * 32 + q * 8;
#pragma unroll
    for (int mt = 0; mt < 2; ++mt)
      accS[mt] = __builtin_amdgcn_mfma_f32_16x16x32_bf16(
          *(const short8*)(ap + mt * 2048), bf, accS[mt], 0, 0, 0);
    const unsigned short* ap2 = ap + 128 * 128;
#pragma unroll
    for (int mt = 0; mt < 2; ++mt)
      accS[2 + mt] = __builtin_amdgcn_mfma_f32_16x16x32_bf16(
          *(const short8*)(ap2 + mt * 2048), bf, accS[2 + mt], 0, 0, 0);
  }
  float s2v[2][4], tssb[2][4];
  {
    float nrm = 0.f;
#pragma unroll
    for (int mt = 0; mt < 2; ++mt) {
      const float4 bb = *(const float4*)(sv_b + rb + mt * 16 + q * 4);
      const float* bp = (const float*)&bb;
#pragma unroll
      for (int r = 0; r < 4; ++r) {
        const float tv = accS[mt][r] + bp[r];
        s2v[mt][r] = tv;
        nrm += tv * tv;
      }
    }
    nrm += __shfl_xor(nrm, 16);
    nrm += __shfl_xor(nrm, 32);
    if (lane < 16) xred[0][rg][mycol] = nrm;
    __syncthreads();  // B2
    const float ntot = xred[0][0][mycol] + xred[0][1][mycol] +
                       xred[0][2][mycol] + xred[0][3][mycol];
    const float inv = 1.f / fmaxf(sqrtf(ntot), EPS);
#pragma unroll
    for (int mt = 0; mt < 2; ++mt)
#pragma unroll
      for (int r = 0; r < 4; ++r) s2v[mt][r] *= inv;
#pragma unroll
    for (int mt = 0; mt < 2; ++mt) {
      const float4 b1 = *(const float4*)(ss_b + rb + mt * 16 + q * 4);
      const float4 b2 = *(const float4*)(vs_b + rb + mt * 16 + q * 4);
      const float* p1 = (const float*)&b1;
      const float* p2 = (const float*)&b2;
#pragma unroll
      for (int r = 0; r < 4; ++r) tssb[mt][r] = accS[2 + mt][r] + p1[r] + p2[r];
    }
  }

  // ---- g1: dd (vsdir rows rb..rb+31) + means-row tile (row 386 = ones/128) ----
  floatx4 accD[3][3];
#pragma unroll
  for (int i = 0; i < 3; ++i)
#pragma unroll
    for (int v = 0; v < 3; ++v) accD[i][v] = (floatx4){0.f, 0.f, 0.f, 0.f};
#pragma unroll
  for (int k = 0; k < 4; ++k) {
    short8 bfv[3];
#pragma unroll
    for (int v = 0; v < 3; ++v)
      bfv[v] = *(const short8*)(xB + (v * 32 + mycol) * 136 + k * 32 + q * 8);
    const unsigned short* ap = wsu + WS_AMAIN + (256 + rb + ln) * 128 + k * 32 + q * 8;
#pragma unroll
    for (int i = 0; i < 2; ++i) {
      const short8 a = *(const short8*)(ap + i * 2048);
#pragma unroll
      for (int v = 0; v < 3; ++v)
        accD[i][v] = __builtin_amdgcn_mfma_f32_16x16x32_bf16(a, bfv[v], accD[i][v], 0, 0, 0);
    }
    const unsigned short* am = wsu + WS_AMAIN + (384 + ln) * 128 + k * 32 + q * 8;
    const short8 a4 = *(const short8*)am;
#pragma unroll
    for (int v = 0; v < 3; ++v)
      accD[2][v] = __builtin_amdgcn_mfma_f32_16x16x32_bf16(a4, bfv[v], accD[2][v], 0, 0, 0);
  }
  float xm[3];
#pragma unroll
  for (int v = 0; v < 3; ++v) xm[v] = __shfl(accD[2][v][2], ln);  // row 386

  // ---- scalar path: sfv -> sfn -> LDS (over sB, own k-range) ----
  {
    float sfv[2][4];
    float ssum = 0.f;
#pragma unroll
    for (int mt = 0; mt < 2; ++mt) {
      const float4 rs4 = *(const float4*)(vdr + rb + mt * 16 + q * 4);
      const float* rp = (const float*)&rs4;
      uint2 pk[3];
#pragma unroll
      for (int v = 0; v < 3; ++v)
        pk[v] = *(const uint2*)(xB + (v * 32 + mycol) * 136 + rb + mt * 16 + q * 4);
#pragma unroll
      for (int r = 0; r < 4; ++r) {
        float d[3], xr[3];
#pragma unroll
        for (int v = 0; v < 3; ++v) {
          d[v] = accD[mt][v][r] - rp[r] * xm[v];
          const unsigned w = (r < 2) ? pk[v].x : pk[v].y;
          xr[v] = bf2f((w >> ((r & 1) * 16)) & 0xffffu) - xm[v];
        }
        const float n2 = d[0] * d[0] + d[1] * d[1] + d[2] * d[2];
        const float dinv = 1.f / fmaxf(sqrtf(n2), EPS);
        const float sv_ = (xr[0] * d[0] + xr[1] * d[1] + xr[2] * d[2]) * dinv;
        sfv[mt][r] = sv_;
        ssum += sv_ * sv_;
      }
    }
    ssum += __shfl_xor(ssum, 16);
    ssum += __shfl_xor(ssum, 32);
    if (lane < 16) xred[1][rg][mycol] = ssum;
    __syncthreads();  // B3
    const float stot = xred[1][0][mycol] + xred[1][1][mycol] +
                       xred[1][2][mycol] + xred[1][3][mycol];
    const float sinv = 1.f / fmaxf(sqrtf(stot), EPS);
#pragma unroll
    for (int mt = 0; mt < 2; ++mt) {
      const unsigned lo = (unsigned)f2bf(sfv[mt][0] * sinv) |
                          ((unsigned)f2bf(sfv[mt][1] * sinv) << 16);
      const unsigned hi = (unsigned)f2bf(sfv[mt][2] * sinv) |
                          ((unsigned)f2bf(sfv[mt][3] * sinv) << 16);
      *(uint2*)(sB + mycol * 136 + rb + mt * 16 + q * 4) = make_uint2(lo, hi);
    }
  }

  // ---- g2a: v1 = W1se3@x (rows rb..rb+31); vmn in-kernel; v2; write v2B ----
  floatx4 accV[2][3];
#pragma unroll
  for (int i = 0; i < 2; ++i)
#pragma unroll
    for (int v = 0; v < 3; ++v) accV[i][v] = (floatx4){0.f, 0.f, 0.f, 0.f};
#pragma unroll
  for (int k = 0; k < 4; ++k) {
    short8 bfv[3];
#pragma unroll
    for (int v = 0; v < 3; ++v)
      bfv[v] = *(const short8*)(xB + (v * 32 + mycol) * 136 + k * 32 + q * 8);
    const unsigned short* ap = wsu + WS_AMAIN + (rb + ln) * 128 + k * 32 + q * 8;
#pragma unroll
    for (int mt = 0; mt < 2; ++mt) {
      const short8 a = *(const short8*)(ap + mt * 2048);
#pragma unroll
      for (int v = 0; v < 3; ++v)
        accV[mt][v] = __builtin_amdgcn_mfma_f32_16x16x32_bf16(a, bfv[v], accV[mt][v], 0, 0, 0);
    }
  }
  // vmn = mean over 128 output rows of v1 (fp32, matches reference mean(axis=1))
#pragma unroll
  for (int v = 0; v < 3; ++v) {
    float s = 0.f;
#pragma unroll
    for (int mt = 0; mt < 2; ++mt)
#pragma unroll
      for (int r = 0; r < 4; ++r) s += accV[mt][v][r];
    s += __shfl_xor(s, 16);
    s += __shfl_xor(s, 32);
    if (lane < 16) xred[2 + v][rg][mycol] = s;
  }
  __syncthreads();  // B4a
  float vmn[3], v2m[3];
#pragma unroll
  for (int v = 0; v < 3; ++v)
    vmn[v] = (xred[2 + v][0][mycol] + xred[2 + v][1][mycol] +
              xred[2 + v][2][mycol] + xred[2 + v][3][mycol]) * (1.f / 128.f);
#pragma unroll
  for (int v = 0; v < 3; ++v) {
    float s = 0.f;
#pragma unroll
    for (int mt = 0; mt < 2; ++mt)
#pragma unroll
      for (int r = 0; r < 4; ++r) {
        const float val = (accV[mt][v][r] - vmn[v]) * s2v[mt][r] + vmn[v];
        accV[mt][v][r] = val;
        s += val;
      }
    s += __shfl_xor(s, 16);
    s += __shfl_xor(s, 32);
    if (lane < 16) xred[5 + v][rg][mycol] = s;
  }
  __syncthreads();  // B4b
#pragma unroll
  for (int v = 0; v < 3; ++v)
    v2m[v] = (xred[5 + v][0][mycol] + xred[5 + v][1][mycol] +
              xred[5 + v][2][mycol] + xred[5 + v][3][mycol]) * (1.f / 128.f);
#pragma unroll
  for (int mt = 0; mt < 2; ++mt)
#pragma unroll
    for (int v = 0; v < 3; ++v) {
      const unsigned lo = (unsigned)f2bf(accV[mt][v][0]) |
                          ((unsigned)f2bf(accV[mt][v][1]) << 16);
      const unsigned hi = (unsigned)f2bf(accV[mt][v][2]) |
                          ((unsigned)f2bf(accV[mt][v][3]) << 16);
      *(uint2*)(v2B + (v * 32 + mycol) * 136 + rb + mt * 16 + q * 4) = make_uint2(lo, hi);
    }

  // ---- g2b: vd = W2se3@x (rows rb..rb+31); dmn in-kernel; cross; cr over xB ----
  floatx4 accW[2][3];
#pragma unroll
  for (int i = 0; i < 2; ++i)
#pragma unroll
    for (int v = 0; v < 3; ++v) accW[i][v] = (floatx4){0.f, 0.f, 0.f, 0.f};
#pragma unroll
  for (int k = 0; k < 4; ++k) {
    short8 bfv[3];
#pragma unroll
    for (int v = 0; v < 3; ++v)
      bfv[v] = *(const short8*)(xB + (v * 32 + mycol) * 136 + k * 32 + q * 8);
    const unsigned short* ap = wsu + WS_AMAIN + (128 + rb + ln) * 128 + k * 32 + q * 8;
#pragma unroll
    for (int mt = 0; mt < 2; ++mt) {
      const short8 a = *(const short8*)(ap + mt * 2048);
#pragma unroll
      for (int v = 0; v < 3; ++v)
        accW[mt][v] = __builtin_amdgcn_mfma_f32_16x16x32_bf16(a, bfv[v], accW[mt][v], 0, 0, 0);
    }
  }
  // dmn = mean over 128 rows of vd
#pragma unroll
  for (int v = 0; v < 3; ++v) {
    float s = 0.f;
#pragma unroll
    for (int mt = 0; mt < 2; ++mt)
#pragma unroll
      for (int r = 0; r < 4; ++r) s += accW[mt][v][r];
    s += __shfl_xor(s, 16);
    s += __shfl_xor(s, 32);
    if (lane < 16) xred[2 + v][rg][mycol] = s;  // reuse 2-4 (read side ended pre-B4b)
  }
  __syncthreads();  // B5a
  float dmn[3];
#pragma unroll
  for (int v = 0; v < 3; ++v)
    dmn[v] = (xred[2 + v][0][mycol] + xred[2 + v][1][mycol] +
              xred[2 + v][2][mycol] + xred[2 + v][3][mycol]) * (1.f / 128.f);
  float an[2][4];
  float csum = 0.f;
#pragma unroll
  for (int mt = 0; mt < 2; ++mt)
#pragma unroll
    for (int r = 0; r < 4; ++r) {
      const float a0 = accW[mt][0][r] - dmn[0];
      const float a1 = accW[mt][1][r] - dmn[1];
      const float a2 = accW[mt][2][r] - dmn[2];
      accW[mt][0][r] = a0; accW[mt][1][r] = a1; accW[mt][2][r] = a2;
      const float n2 = a0 * a0 + a1 * a1 + a2 * a2;
      an[mt][r] = sqrtf(n2);
      csum += n2;
    }
  csum += __shfl_xor(csum, 16);
  csum += __shfl_xor(csum, 32);
  if (lane < 16) xred[0][rg][mycol] = csum;  // reuse 0 (read side ended pre-B3)
  __syncthreads();  // B5b (all x-reads of xB complete)
  const float ctot = xred[0][0][mycol] + xred[0][1][mycol] +
                     xred[0][2][mycol] + xred[0][3][mycol];
  const float cninv = 1.f / fmaxf(sqrtf(ctot), EPS);
#pragma unroll
  for (int mt = 0; mt < 2; ++mt) {
    float crv[3][4];
#pragma unroll
    for (int r = 0; r < 4; ++r) {
      const float sc = an[mt][r] / fmaxf(an[mt][r], EPS) * cninv;
      const float h0 = accW[mt][0][r] * sc;
      const float h1 = accW[mt][1][r] * sc;
      const float h2 = accW[mt][2][r] * sc;
      const float w0 = accV[mt][0][r], w1 = accV[mt][1][r], w2 = accV[mt][2][r];
      const float g0 = w0 - v2m[0], g1 = w1 - v2m[1], g2 = w2 - v2m[2];
      crv[0][r] = h1 * g2 - h2 * g1 + w0;
      crv[1][r] = h2 * g0 - h0 * g2 + w1;
      crv[2][r] = h0 * g1 - h1 * g0 + w2;
    }
#pragma unroll
    for (int v = 0; v < 3; ++v) {
      const unsigned lo = (unsigned)f2bf(crv[v][0]) | ((unsigned)f2bf(crv[v][1]) << 16);
      const unsigned hi = (unsigned)f2bf(crv[v][2]) | ((unsigned)f2bf(crv[v][3]) << 16);
      *(uint2*)(xB + (v * 32 + mycol) * 136 + rb + mt * 16 + q * 4) = make_uint2(lo, hi);
    }
  }
  __syncthreads();  // B6: cr/v2/sfn complete -> g3 may read full K

  // ---- g3: crossfc (K=256 over [cr;v2]) + vs (K=128 over sfn) GEMMs ----
  floatx4 accO[2][3];
  floatx4 accP[2];
#pragma unroll
  for (int i = 0; i < 2; ++i) {
    accP[i] = (floatx4){0.f, 0.f, 0.f, 0.f};
#pragma unroll
    for (int v = 0; v < 3; ++v) accO[i][v] = (floatx4){0.f, 0.f, 0.f, 0.f};
  }
#pragma unroll
  for (int ks = 0; ks < 8; ++ks) {
    const unsigned short* src = (ks < 4) ? xB : v2B;
    const int kk = ks & 3;
    short8 bfv[3];
#pragma unroll
    for (int v = 0; v < 3; ++v)
      bfv[v] = *(const short8*)(src + (v * 32 + mycol) * 136 + kk * 32 + q * 8);
    const unsigned short* afc = wsu + WS_AFC + (rb + ln) * 256 + ks * 32 + q * 8;
#pragma unroll
    for (int mt = 0; mt < 2; ++mt) {
      const short8 a = *(const short8*)(afc + mt * 4096);
#pragma unroll
      for (int v = 0; v < 3; ++v)
        accO[mt][v] = __builtin_amdgcn_mfma_f32_16x16x32_bf16(a, bfv[v], accO[mt][v], 0, 0, 0);
    }
    if (ks < 4) {
      const short8 bfs = *(const short8*)(sB + mycol * 136 + kk * 32 + q * 8);
      const unsigned short* avs = wsu + WS_AVS + (rb + ln) * 128 + kk * 32 + q * 8;
#pragma unroll
      for (int mt = 0; mt < 2; ++mt)
        accP[mt] = __builtin_amdgcn_mfma_f32_16x16x32_bf16(
            *(const short8*)(avs + mt * 2048), bfs, accP[mt], 0, 0, 0);
    }
  }

  // ---- epilogue stores (rows rb..rb+31) ----
  const int gc = n0 + mycol;
  float* vob = v_out + (size_t)b * (128 * 3 * 4096) + gc;
  float* sob = s_out + (size_t)b * (128 * 4096) + gc;
#pragma unroll
  for (int mt = 0; mt < 2; ++mt)
#pragma unroll
    for (int r = 0; r < 4; ++r) {
      const int o = rb + mt * 16 + q * 4 + r;
#pragma unroll
      for (int v = 0; v < 3; ++v)
        vob[(size_t)(o * 3 + v) * 4096] = accO[mt][v][r];
      sob[(size_t)o * 4096] = accP[mt][r] + tssb[mt][r];
    }
}

extern "C" void kernel_launch(void* const* d_in, const int* in_sizes, int n_in,
                              void* d_out, int out_size, void* d_ws, size_t ws_size,
                              hipStream_t stream) {
  const float* v_in      = (const float*)d_in[0];
  const float* s_in      = (const float*)d_in[1];
  const float* weight    = (const float*)d_in[2];
  const float* sv_W      = (const float*)d_in[3];
  const float* sv_b      = (const float*)d_in[4];
  const float* cross_w   = (const float*)d_in[5];
  const float* crossfc_w = (const float*)d_in[6];
  const float* vsdir_w   = (const float*)d_in[7];
  const float* vs_W      = (const float*)d_in[8];
  const float* vs_b      = (const float*)d_in[9];
  const float* ss_W      = (const float*)d_in[10];
  const float* ss_b      = (const float*)d_in[11];

  float* out = (float*)d_out;
  float* v_out = out;                                  // [16][128][3][4096]
  float* s_out = out + (size_t)16 * 128 * 3 * 4096;    // [16][128][4096]
  unsigned short* wsu = (unsigned short*)d_ws;
  float* vdr = (float*)((char*)d_ws + WS_VDR_B);

  hipLaunchKernelGGL(k_pre, dim3(128), dim3(256), 0, stream,
                     weight, sv_W, cross_w, crossfc_w, vsdir_w, vs_W, ss_W, wsu, vdr);
  hipLaunchKernelGGL(k_main, dim3(2048), dim3(512), 0, stream,
                     v_in, s_in, wsu, vdr, sv_b, vs_b, ss_b, v_out, s_out);
}